// Round 2
// baseline (699.255 us; speedup 1.0000x reference)
//
#include <hip/hip_runtime.h>
#include <math.h>

#define B_N 256
#define T_N 1024
#define D_N 128
#define H_N 256
#define NSEG 8     // t-segments per b; each block covers 128 t

// LDS (shorts): wave-private single-buffered activations (32 rows x SPS each),
// 8-short guard (zeroed, catches last-row K-overrun b128 reads), accum floats.
#define SPS 120                   // 112 cols + pad; 16B-unit stride 15 (odd) -> conflict-free
#define SACT_SH (4 * 32 * SPS)    // 15360
#define ACC_OFF (SACT_SH + 8)     // guard at [15360,15368)
#define SMEM_SH (ACC_OFF + 512)   // 15880 shorts = 31,760 B

typedef __attribute__((ext_vector_type(8))) short short8;   // 8 bf16 = 4 VGPRs
typedef __attribute__((ext_vector_type(4))) float f32x4;

// ws layout (bf16 units): weights in MFMA fragment order; each B-fragment is
// ONE coalesced 1KB global_load_dwordx4 (lane i reads bytes [16i,16i+16)).
//   elem index within layer: ((nt*KR + k4)*64 + lane)*8 + j
//   holds WT[n = nt*16 + (lane&15)][k = k4*32 + (lane>>4)*8 + j], zero-padded.
#define WXT_OFF 0         // NT=16 KR=4 -> 32768
#define W1T_OFF 32768     // NT=7  KR=4 -> 14336
#define W2T_OFF 47104     // NT=7  KR=4 -> 14336   rows k>=100 ZERO
#define W3T_OFF 61440     // NT=7  KR=4 -> 14336
#define W4T_OFF 75776     // NT=4  KR=4 ->  8192
#define W5T_OFF 83968     // NT=16 KR=2 -> 16384   rows k>=50 zero
#define WT_TOTAL 100352
// done-counters: 256 ints right after the weights in ws (byte off 200,704)

__device__ __forceinline__ float sigmoid_f(float z) {
    return 1.0f / (1.0f + __expf(-z));
}
__device__ __forceinline__ unsigned short f2bf(float f) {   // RNE fp32->bf16
    unsigned u = __float_as_uint(f);
    return (unsigned short)((u + 0x7FFFu + ((u >> 16) & 1u)) >> 16);
}

// ---- prep: fp32 W[K][N] -> bf16 fragment-ordered + zero out[] and cnt[]
__global__ __launch_bounds__(256) void prep_init(
    const float* __restrict__ Wx, const float* __restrict__ W1,
    const float* __restrict__ W2, const float* __restrict__ W3,
    const float* __restrict__ W4, const float* __restrict__ W5,
    short* __restrict__ wt, float* __restrict__ out, int* __restrict__ cnt)
{
    int idx = blockIdx.x * 256 + threadIdx.x;
    // zero out (65792 floats = 16448 float4) + cnt (256 ints)
    if (idx < 16448) {
        const float4 z = {0.f, 0.f, 0.f, 0.f};
        reinterpret_cast<float4*>(out)[idx] = z;
    } else if (idx < 16448 + 256) {
        cnt[idx - 16448] = 0;
    }
    if (idx >= WT_TOTAL) return;
    const float* src; int base, KR, K, N;
    if (idx < W1T_OFF)      { src = Wx; base = WXT_OFF; KR = 4; K = 128; N = 256; }
    else if (idx < W2T_OFF) { src = W1; base = W1T_OFF; KR = 4; K = 128; N = 100; }
    else if (idx < W3T_OFF) { src = W2; base = W2T_OFF; KR = 4; K = 100; N = 100; }
    else if (idx < W4T_OFF) { src = W3; base = W3T_OFF; KR = 4; K = 100; N = 100; }
    else if (idx < W5T_OFF) { src = W4; base = W4T_OFF; KR = 4; K = 100; N =  50; }
    else                    { src = W5; base = W5T_OFF; KR = 2; K =  50; N = 256; }
    int e    = idx - base;
    int j    = e & 7;
    int slot = e >> 3;            // (nt*KR + k4)*64 + lane
    int lane = slot & 63;
    int kk   = slot >> 6;
    int k4   = kk & (KR - 1);
    int nt   = kk / KR;
    int n = nt * 16 + (lane & 15);
    int k = k4 * 32 + (lane >> 4) * 8 + j;
    float v = (k < K && n < N) ? src[(size_t)k * N + n] : 0.0f;
    wt[idx] = (short)f2bf(v);
}

// Load both row-blocks' A-fragments (K=128) from wave-private LDS acts.
__device__ __forceinline__ void loadA2(const short* __restrict__ sA, short8 (&a)[2][4],
                                       int lr, int lq)
{
    #pragma unroll
    for (int rb = 0; rb < 2; ++rb)
        #pragma unroll
        for (int k = 0; k < 4; ++k)
            a[rb][k] = *reinterpret_cast<const short8*>(&sA[(rb * 16 + lr) * SPS + k * 32 + lq * 8]);
}

// Dense layer over 32 rows: B-fragment loaded ONCE from global (fragment order,
// L1/L2-hot), reused by TWO MFMAs (independent acc chains). relu+bf16 store of
// own rows (wave-private region -> no barrier; writes data-depend on the reads).
template<int NT>
__device__ __forceinline__ void denseL2(const short8 (&a)[2][4], const short* __restrict__ gW,
                                        const float* __restrict__ bias, int ncap,
                                        short* __restrict__ sA, int lr, int lq, int lane)
{
    #pragma unroll 2
    for (int nt = 0; nt < NT; ++nt) {
        const int n0 = nt * 16;
        f32x4 acc0 = {0.f, 0.f, 0.f, 0.f};
        f32x4 acc1 = {0.f, 0.f, 0.f, 0.f};
        #pragma unroll
        for (int k = 0; k < 4; ++k) {
            const short8 bf = *reinterpret_cast<const short8*>(&gW[((nt * 4 + k) * 64 + lane) * 8]);
            acc0 = __builtin_amdgcn_mfma_f32_16x16x32_bf16(a[0][k], bf, acc0, 0, 0, 0);
            acc1 = __builtin_amdgcn_mfma_f32_16x16x32_bf16(a[1][k], bf, acc1, 0, 0, 0);
        }
        const bool valid = (n0 + lr < ncap);
        const float bv = valid ? bias[n0 + lr] : 0.0f;
        #pragma unroll
        for (int r = 0; r < 4; ++r) {
            float v0 = valid ? fmaxf(acc0[r] + bv, 0.0f) : 0.0f;
            float v1 = valid ? fmaxf(acc1[r] + bv, 0.0f) : 0.0f;
            sA[(lq * 4 + r) * SPS + n0 + lr]        = (short)f2bf(v0);
            sA[(16 + lq * 4 + r) * SPS + n0 + lr]   = (short)f2bf(v1);
        }
    }
}

// Fused MLP + linearized scan + (for the last block per b) the output head.
//   hidden[b,h] = sum_t gate[t,b,(h - s*(T-1-t)) mod H]
// Grid 2048 = 8 t-segments x 256 batch; block = 4 waves x 32 t-rows each.
__global__ __launch_bounds__(256, 4) void srnn_gate_scan(
    const float* __restrict__ x, const short* __restrict__ wt,
    const float* __restrict__ bx, const float* __restrict__ b1,
    const float* __restrict__ b2, const float* __restrict__ b3,
    const float* __restrict__ b4, const float* __restrict__ b5,
    const int* __restrict__ shiftp,
    const float* __restrict__ Wo, const float* __restrict__ bo,
    int* __restrict__ cnt,
    float* __restrict__ out)   // out[0..255]=output, out[256..]=hidden
{
    __shared__ __align__(16) short smem[SMEM_SH];
    float* accum = reinterpret_cast<float*>(smem + ACC_OFF);

    const int tid  = threadIdx.x;
    const int b    = blockIdx.x & 255;
    const int seg  = blockIdx.x >> 8;      // 0..7
    const int lane = tid & 63;
    const int wid  = tid >> 6;
    const int lr = lane & 15;              // A m-index / B n-index / C-D col
    const int lq = lane >> 4;              // quad; C/D row = lq*4+r
    const int s  = *shiftp;
    const int tw0 = seg * 128 + wid * 32;  // wave's first t
    short* sA = smem + wid * 32 * SPS;     // wave-private activation rows

    // zero ALL of LDS (act pads + guard finite; accum zeroed for atomics)
    {
        const float4 z = {0.f, 0.f, 0.f, 0.f};
        float4* dst = reinterpret_cast<float4*>(smem);
        #pragma unroll
        for (int i = 0; i < 8; ++i) {
            int sl = tid + i * 256;
            if (sl < SMEM_SH / 8) dst[sl] = z;
        }
    }

    // x A-fragments straight from global (row = lr per lane), f2bf in regs
    short8 ax[2][4];
    #pragma unroll
    for (int rb = 0; rb < 2; ++rb) {
        const float* xr = x + ((size_t)b * T_N + tw0 + rb * 16 + lr) * D_N;
        #pragma unroll
        for (int k = 0; k < 4; ++k) {
            const float4 v0 = *reinterpret_cast<const float4*>(&xr[k * 32 + lq * 8]);
            const float4 v1 = *reinterpret_cast<const float4*>(&xr[k * 32 + lq * 8 + 4]);
            short8 t;
            t[0] = (short)f2bf(v0.x); t[1] = (short)f2bf(v0.y);
            t[2] = (short)f2bf(v0.z); t[3] = (short)f2bf(v0.w);
            t[4] = (short)f2bf(v1.x); t[5] = (short)f2bf(v1.y);
            t[6] = (short)f2bf(v1.z); t[7] = (short)f2bf(v1.w);
            ax[rb][k] = t;
        }
    }
    __syncthreads();                       // zero-init visible to all waves

    // ---- MLP chain, zero barriers (wave-private rows, in-order DS pipe)
    short8 aL[2][4];
    denseL2<7>(ax, wt + W1T_OFF, b1, 100, sA, lr, lq, lane);
    loadA2(sA, aL, lr, lq);
    denseL2<7>(aL, wt + W2T_OFF, b2, 100, sA, lr, lq, lane);
    loadA2(sA, aL, lr, lq);
    denseL2<7>(aL, wt + W3T_OFF, b3, 100, sA, lr, lq, lane);
    loadA2(sA, aL, lr, lq);
    denseL2<4>(aL, wt + W4T_OFF, b4, 50, sA, lr, lq, lane);

    // L4 output as K=64 A-fragments for L5 (cols 50..63 zero from ncap)
    short8 c[2][2];
    #pragma unroll
    for (int rb = 0; rb < 2; ++rb) {
        c[rb][0] = *reinterpret_cast<const short8*>(&sA[(rb * 16 + lr) * SPS + 0 + lq * 8]);
        c[rb][1] = *reinterpret_cast<const short8*>(&sA[(rb * 16 + lr) * SPS + 32 + lq * 8]);
    }

    // ---- tail: Lx (A=ax) + L5 (A=c) + gate + scatter, 16 n-tiles, both rbs
    const short* gWx = wt + WXT_OFF;
    const short* gW5 = wt + W5T_OFF;
    const int tbase = T_N - 1 - tw0;
    #pragma unroll 2
    for (int ntl = 0; ntl < 16; ++ntl) {
        const int n0 = ntl * 16;
        f32x4 axv0 = {0.f, 0.f, 0.f, 0.f};
        f32x4 axv1 = {0.f, 0.f, 0.f, 0.f};
        #pragma unroll
        for (int k = 0; k < 4; ++k) {
            const short8 bf = *reinterpret_cast<const short8*>(&gWx[((ntl * 4 + k) * 64 + lane) * 8]);
            axv0 = __builtin_amdgcn_mfma_f32_16x16x32_bf16(ax[0][k], bf, axv0, 0, 0, 0);
            axv1 = __builtin_amdgcn_mfma_f32_16x16x32_bf16(ax[1][k], bf, axv1, 0, 0, 0);
        }
        f32x4 a5v0 = {0.f, 0.f, 0.f, 0.f};
        f32x4 a5v1 = {0.f, 0.f, 0.f, 0.f};
        {
            const short8 bf0 = *reinterpret_cast<const short8*>(&gW5[((ntl * 2 + 0) * 64 + lane) * 8]);
            const short8 bf1 = *reinterpret_cast<const short8*>(&gW5[((ntl * 2 + 1) * 64 + lane) * 8]);
            a5v0 = __builtin_amdgcn_mfma_f32_16x16x32_bf16(c[0][0], bf0, a5v0, 0, 0, 0);
            a5v1 = __builtin_amdgcn_mfma_f32_16x16x32_bf16(c[1][0], bf0, a5v1, 0, 0, 0);
            a5v0 = __builtin_amdgcn_mfma_f32_16x16x32_bf16(c[0][1], bf1, a5v0, 0, 0, 0);
            a5v1 = __builtin_amdgcn_mfma_f32_16x16x32_bf16(c[1][1], bf1, a5v1, 0, 0, 0);
        }
        const float bxv = bx[n0 + lr];
        const float b5v = b5[n0 + lr];
        #pragma unroll
        for (int rb = 0; rb < 2; ++rb) {
            const f32x4& axv = rb ? axv1 : axv0;
            const f32x4& a5v = rb ? a5v1 : a5v0;
            #pragma unroll
            for (int r = 0; r < 4; ++r) {
                const int toff = rb * 16 + lq * 4 + r;
                // sigmoid(a)*sigmoid(b) = 1/((1+e^-a)(1+e^-b)): one rcp
                const float ea = __expf(-(a5v[r] + b5v));
                const float eb = __expf(-(axv[r] + bxv));
                const float g = 1.0f / ((1.0f + ea) * (1.0f + eb));
                // (unsigned)v & 255 == v mod 256 (2^32 % 256 == 0)
                const int h = (int)(((unsigned)(n0 + lr + s * (tbase - toff))) & 255u);
                atomicAdd(&accum[h], g);   // per-t the h-map is a bijection
            }
        }
    }
    __syncthreads();

    // flush partial hidden (8 segment-blocks per b -> global atomic, out zeroed)
    atomicAdd(&out[256 + b * 256 + tid], accum[tid]);
    __threadfence();                       // release our hidden adds
    __syncthreads();

    // last block for this b computes output[b] = sigmoid(hidden . Wo + bo)
    int* flag = reinterpret_cast<int*>(accum);
    if (tid == 0) {
        const int old = atomicAdd(&cnt[b], 1);       // device-scope RMW
        __threadfence();                              // acquire
        flag[0] = (old == NSEG - 1) ? 1 : 0;
    }
    __syncthreads();
    if (!flag[0]) return;

    const float hv = __hip_atomic_load(&out[256 + b * 256 + tid],
                                       __ATOMIC_RELAXED, __HIP_MEMORY_SCOPE_AGENT);
    const float pv = hv * Wo[tid];
    __syncthreads();                       // flag read done before accum reuse
    accum[tid] = pv;
    __syncthreads();
    #pragma unroll
    for (int off = 128; off > 0; off >>= 1) {
        if (tid < off) accum[tid] += accum[tid + off];
        __syncthreads();
    }
    if (tid == 0) out[b] = sigmoid_f(accum[0] + bo[0]);
}

extern "C" void kernel_launch(void* const* d_in, const int* in_sizes, int n_in,
                              void* d_out, int out_size, void* d_ws, size_t ws_size,
                              hipStream_t stream)
{
    const float* x  = (const float*)d_in[0];
    const float* Wx = (const float*)d_in[1];
    const float* bx = (const float*)d_in[2];
    const float* W1 = (const float*)d_in[3];
    const float* b1 = (const float*)d_in[4];
    const float* W2 = (const float*)d_in[5];
    const float* b2 = (const float*)d_in[6];
    const float* W3 = (const float*)d_in[7];
    const float* b3 = (const float*)d_in[8];
    const float* W4 = (const float*)d_in[9];
    const float* b4 = (const float*)d_in[10];
    const float* W5 = (const float*)d_in[11];
    const float* b5 = (const float*)d_in[12];
    const float* Wo = (const float*)d_in[13];
    const float* bo = (const float*)d_in[14];
    const int* shiftp = (const int*)d_in[15];
    float* out = (float*)d_out;
    short* wt  = (short*)d_ws;                       // 200,704 B: bf16 fragment-ordered weights
    int* cnt   = (int*)((char*)d_ws + WT_TOTAL * 2); // 256 done-counters (1 KB)

    // prep zeroes out[] and cnt[] -> no hipMemsetAsync dispatch needed
    prep_init<<<dim3((WT_TOTAL + 255) / 256), dim3(256), 0, stream>>>(
        Wx, W1, W2, W3, W4, W5, wt, out, cnt);
    srnn_gate_scan<<<dim3(2048), dim3(256), 0, stream>>>(
        x, wt, bx, b1, b2, b3, b4, b5, shiftp, Wo, bo, cnt, out);
}